// Round 12
// baseline (13216.460 us; speedup 1.0000x reference)
//
#include <hip/hip_runtime.h>

// Stacked LSTM (100/80/50/30) + dense head, fp32 semantics via bf16x3 MFMA.
//
// R12: layer-PIPELINED persistent kernel + coalesced H traffic.
//   R11 counters: MfmaUtil 3.4%, VALUBusy 7.5%, Occ 3% -> latency-bound,
//   90% idle; scattered per-lane Hpk stores (64 transactions/instr) and
//   4 strictly-sequential layers on 32/256 CUs were the structure.
//   - One fused kernel, grid = 4 layers x 32 chunks (blockIdx = 32*l + b:
//     chunk chain stays on one XCD -> L2-local handoff).
//   - Flags: flag[l][b] = #steps published (monotonic u32). Producer:
//     coalesced H stores (LDS-staged) -> __threadfence -> barrier -> tid0
//     agent-release store. Consumer: agent-acquire spin (steady-state: one
//     load), then coalesced H loads. Producers never wait -> deadlock-free
//     (128 blocks <= 256 CUs, all co-resident).
//   - Flags zeroed by a prologue kernel every call (graph-replay safe).
//   - ws_size checked: pipelined needs H0+H1+H2 = 241MB; else fall back to
//     4 sequential launches of the SAME kernel (pipe=0, H2 aliases H0).
//   - bf16x3 numerics (z = Wh*ah + Wl*ah + Wh*al) proven: absmax 7.6e-6.

#define T_SEQ 512
#define B_TOT 512

typedef __attribute__((ext_vector_type(8))) short short8;   // 8 bf16
typedef __attribute__((ext_vector_type(4))) float f32x4;

__device__ __forceinline__ unsigned short bf16_rne(float f) {
    unsigned u = __float_as_uint(f);
    u += 0x7FFFu + ((u >> 16) & 1u);
    return (unsigned short)(u >> 16);
}
__device__ __forceinline__ float bf16_to_f(unsigned short h) {
    return __uint_as_float(((unsigned)h) << 16);
}
__device__ __forceinline__ float sigmoidf_(float x) {
    return 1.0f / (1.0f + __expf(-x));
}
__device__ __forceinline__ float tanh_fast(float x) {
    float e = __expf(2.0f * x);
    return 1.0f - 2.0f / (1.0f + e);
}

// U: real units, UP: padded units (mult 4), FI: input feats, KT: K-tiles of
// 32, SLOTS: weight slots/wave. XF32: input is fp32 (layer 0). SEQ: publish
// hidden sequence. FINAL: dense head.
template<int U, int UP, int FI, int KT, int SLOTS, bool XF32, bool SEQ, bool FINAL>
__device__ __forceinline__ void run_layer(
    int chunk, bool pipe,
    const float* Xf, const unsigned* Hin, unsigned* flg_in,
    const float* W, const float* Bv,
    unsigned* Hout, unsigned* flg_out,
    const float* Wd, const float* bd, float* OUT)
{
    constexpr int DIN  = U + FI;
    constexpr int G    = 4 * U;
    constexpr int NT   = UP / 4;
    constexpr int KP   = KT * 32;
    static_assert(KP >= DIN, "K padding must cover DIN");
    constexpr int KPPS = KT * 32 + 8;                  // row stride (shorts), 16B-mult
    constexpr int XIT  = XF32 ? 1 : (16 * FI + 511) / 512;
    constexpr int SIT  = SEQ ? (16 * U + 511) / 512 : 1;
    static_assert(8 * SLOTS >= NT, "slots must cover tiles");

    __shared__ __align__(16) short Abuf[2][2][16][KPPS];   // [buf][plane][row][k]
    __shared__ __align__(16) f32x4 btab[NT * 4];
    __shared__ float redu[8][16];

    const int tid  = threadIdx.x;
    const int wid  = tid >> 6;
    const int l15  = tid & 15;
    const int l4   = (tid >> 4) & 3;
    const int brow = chunk * 16;

    // ---- weight fragments (bf16 hi/lo), permuted cols, pinned to AGPR ----
    short8 Wh[SLOTS][KT], Wl[SLOTS][KT];
    #pragma unroll
    for (int s = 0; s < SLOTS; ++s) {
        const int ti = wid + 8 * s;
        #pragma unroll
        for (int kt = 0; kt < KT; ++kt) {
            short8 hh, ll;
            #pragma unroll
            for (int j = 0; j < 8; ++j) {
                const int k    = kt * 32 + l4 * 8 + j;
                const int up   = ti * 4 + (l15 >> 2);
                const int gate = l15 & 3;
                float v = 0.0f;
                if (ti < NT && up < U && k < DIN)
                    v = W[(size_t)k * G + gate * U + up];
                const unsigned short hb = bf16_rne(v);
                hh[j] = (short)hb;
                ll[j] = (short)bf16_rne(v - bf16_to_f(hb));
            }
            Wh[s][kt] = hh; Wl[s][kt] = ll;
            asm("" : "+a"(Wh[s][kt]));
            asm("" : "+a"(Wl[s][kt]));
        }
    }

    // ---- bias table ----
    if (tid < NT * 4) {
        f32x4 b = {0.f, 0.f, 0.f, 0.f};
        if (tid < U) { b[0]=Bv[tid]; b[1]=Bv[U+tid]; b[2]=Bv[2*U+tid]; b[3]=Bv[3*U+tid]; }
        btab[tid] = b;
    }

    // ---- consumer (x-in) coalesced map: idx -> (row, u) ----
    int crow[XIT], cu_[XIT]; bool cok[XIT]; size_t cbase[XIT];
    if constexpr (!XF32) {
        #pragma unroll
        for (int it = 0; it < XIT; ++it) {
            const int idx = it * 512 + tid;
            cok[it]  = (idx < 16 * FI);
            crow[it] = cok[it] ? (idx / FI) : 0;
            cu_[it]  = cok[it] ? (idx % FI) : 0;
            cbase[it] = (size_t)(brow + crow[it]) * T_SEQ * FI + cu_[it];
        }
    }
    const int xrow = tid >> 5, xj = (tid & 31) * 2;    // L0: 2 floats/thread
    size_t xfb = 0;
    if constexpr (XF32) xfb = (size_t)(brow + xrow) * T_SEQ * FI + xj;

    // ---- producer (h-out) coalesced map ----
    int srow[SIT], su_[SIT]; bool sok[SIT]; size_t sbase[SIT];
    if constexpr (SEQ) {
        #pragma unroll
        for (int it = 0; it < SIT; ++it) {
            const int idx = it * 512 + tid;
            sok[it]  = (idx < 16 * U);
            srow[it] = sok[it] ? (idx / U) : 0;
            su_[it]  = sok[it] ? (idx % U) : 0;
            sbase[it] = (size_t)(brow + srow[it]) * T_SEQ * U + su_[it];
        }
    }

    // ---- init: zero act buffers; stage x(0) ----
    for (int i = tid; i < 2 * 2 * 16 * KPPS; i += 512) ((short*)Abuf)[i] = 0;
    __syncthreads();
    if constexpr (XF32) {
        const float2 xv = *(const float2*)&Xf[xfb];
        const unsigned short h0 = bf16_rne(xv.x), h1 = bf16_rne(xv.y);
        Abuf[0][0][xrow][U + xj]     = (short)h0;
        Abuf[0][0][xrow][U + xj + 1] = (short)h1;
        Abuf[0][1][xrow][U + xj]     = (short)bf16_rne(xv.x - bf16_to_f(h0));
        Abuf[0][1][xrow][U + xj + 1] = (short)bf16_rne(xv.y - bf16_to_f(h1));
    } else {
        if (pipe) {
            while (__hip_atomic_load(&flg_in[chunk], __ATOMIC_ACQUIRE,
                                     __HIP_MEMORY_SCOPE_AGENT) < 1u)
                __builtin_amdgcn_s_sleep(2);
        }
        #pragma unroll
        for (int it = 0; it < XIT; ++it) if (cok[it]) {
            const unsigned v = Hin[cbase[it]];
            Abuf[0][0][crow[it]][U + cu_[it]] = (short)(v & 0xffffu);
            Abuf[0][1][crow[it]][U + cu_[it]] = (short)(v >> 16);
        }
    }
    __syncthreads();

    float c_[SLOTS], hl_[SLOTS];
    #pragma unroll
    for (int s = 0; s < SLOTS; ++s) { c_[s] = 0.0f; hl_[s] = 0.0f; }

    for (int t = 0; t < T_SEQ; ++t) {
        const int cur = t & 1, nxt = cur ^ 1;
        const bool dopre = (t + 1 < T_SEQ);

        // ---- consumer prefetch x(t+1) -> regs (overlaps MFMA) ----
        float2 xv;
        unsigned xg[XIT];
        if (dopre) {
            if constexpr (XF32) {
                xv = *(const float2*)&Xf[xfb + (size_t)(t + 1) * FI];
            } else {
                if (pipe) {
                    const unsigned want = (unsigned)(t + 2);
                    while (__hip_atomic_load(&flg_in[chunk], __ATOMIC_ACQUIRE,
                                             __HIP_MEMORY_SCOPE_AGENT) < want)
                        __builtin_amdgcn_s_sleep(2);
                }
                #pragma unroll
                for (int it = 0; it < XIT; ++it)
                    if (cok[it]) xg[it] = Hin[cbase[it] + (size_t)(t + 1) * FI];
            }
        }

        // ---- producer: coalesced store of h(t-1) from Abuf[cur] ----
        if constexpr (SEQ) {
            if (t > 0) {
                #pragma unroll
                for (int it = 0; it < SIT; ++it) if (sok[it]) {
                    const unsigned v =
                        (unsigned)(unsigned short)Abuf[cur][0][srow[it]][su_[it]]
                      | ((unsigned)(unsigned short)Abuf[cur][1][srow[it]][su_[it]] << 16);
                    Hout[sbase[it] + (size_t)(t - 1) * U] = v;
                }
            }
        }

        // ---- GEMM: D = W^T-tiles x act, bf16x3 ----
        f32x4 acc[SLOTS];
        #pragma unroll
        for (int s = 0; s < SLOTS; ++s) {
            const int ti = wid + 8 * s;
            acc[s] = (ti < NT) ? btab[ti * 4 + l4] : (f32x4){0.f,0.f,0.f,0.f};
        }
        #pragma unroll
        for (int kt = 0; kt < KT; ++kt) {
            const short8 Ah = *(const short8*)&Abuf[cur][0][l15][kt * 32 + l4 * 8];
            const short8 Al = *(const short8*)&Abuf[cur][1][l15][kt * 32 + l4 * 8];
            #pragma unroll
            for (int s = 0; s < SLOTS; ++s) {
                if (wid + 8 * s < NT) {
                    acc[s] = __builtin_amdgcn_mfma_f32_16x16x32_bf16(Wh[s][kt], Ah, acc[s], 0, 0, 0);
                    acc[s] = __builtin_amdgcn_mfma_f32_16x16x32_bf16(Wl[s][kt], Ah, acc[s], 0, 0, 0);
                    acc[s] = __builtin_amdgcn_mfma_f32_16x16x32_bf16(Wh[s][kt], Al, acc[s], 0, 0, 0);
                }
            }
        }

        // ---- cell update (lane-local) -> Abuf[nxt] h-region ----
        #pragma unroll
        for (int s = 0; s < SLOTS; ++s) {
            const int ti = wid + 8 * s;
            if (ti < NT) {
                const float F  = sigmoidf_(acc[s][0]);
                const float I  = sigmoidf_(acc[s][1]);
                const float Gv = tanh_fast(acc[s][2]);
                const float O  = sigmoidf_(acc[s][3]);
                c_[s] = F * c_[s] + I * Gv;
                const float h = O * tanh_fast(c_[s]);
                hl_[s] = h;
                const int up = ti * 4 + l4;
                if (up < U) {
                    const unsigned short hh = bf16_rne(h);
                    const unsigned short hl = bf16_rne(h - bf16_to_f(hh));
                    Abuf[nxt][0][l15][up] = (short)hh;
                    Abuf[nxt][1][l15][up] = (short)hl;
                }
            }
        }

        // ---- stage x(t+1) -> Abuf[nxt] x-region ----
        if (dopre) {
            if constexpr (XF32) {
                const unsigned short h0 = bf16_rne(xv.x), h1 = bf16_rne(xv.y);
                Abuf[nxt][0][xrow][U + xj]     = (short)h0;
                Abuf[nxt][0][xrow][U + xj + 1] = (short)h1;
                Abuf[nxt][1][xrow][U + xj]     = (short)bf16_rne(xv.x - bf16_to_f(h0));
                Abuf[nxt][1][xrow][U + xj + 1] = (short)bf16_rne(xv.y - bf16_to_f(h1));
            } else {
                #pragma unroll
                for (int it = 0; it < XIT; ++it) if (cok[it]) {
                    Abuf[nxt][0][crow[it]][U + cu_[it]] = (short)(xg[it] & 0xffffu);
                    Abuf[nxt][1][crow[it]][U + cu_[it]] = (short)(xg[it] >> 16);
                }
            }
        }

        if constexpr (SEQ) { if (pipe) __threadfence(); }
        __syncthreads();
        if constexpr (SEQ) {
            if (pipe && tid == 0 && t > 0)
                __hip_atomic_store(&flg_out[chunk], (unsigned)t,
                                   __ATOMIC_RELEASE, __HIP_MEMORY_SCOPE_AGENT);
        }
    }

    // ---- post-loop: publish h(511) (lives in Abuf[0]) ----
    if constexpr (SEQ) {
        #pragma unroll
        for (int it = 0; it < SIT; ++it) if (sok[it]) {
            const unsigned v =
                (unsigned)(unsigned short)Abuf[0][0][srow[it]][su_[it]]
              | ((unsigned)(unsigned short)Abuf[0][1][srow[it]][su_[it]] << 16);
            Hout[sbase[it] + (size_t)(T_SEQ - 1) * U] = v;
        }
        if (pipe) {
            __threadfence();
            __syncthreads();
            if (tid == 0)
                __hip_atomic_store(&flg_out[chunk], (unsigned)T_SEQ,
                                   __ATOMIC_RELEASE, __HIP_MEMORY_SCOPE_AGENT);
        }
    }

    if constexpr (FINAL) {
        const int up = wid * 4 + l4;
        float p = 0.0f;
        if (up < U) p = hl_[0] * Wd[up];
        p += __shfl_xor(p, 16, 64);
        p += __shfl_xor(p, 32, 64);
        if ((tid & 48) == 0) redu[wid][l15] = p;
        __syncthreads();
        if (tid < 16) {
            float a = bd[0];
            #pragma unroll
            for (int w2 = 0; w2 < 8; ++w2) a += redu[w2][tid];
            OUT[brow + tid] = a;
        }
    }
}

__global__ void zero_flags(unsigned* f) {
    if (threadIdx.x < 128) f[threadIdx.x] = 0;
}

__global__ __launch_bounds__(512, 1)
void lstm_all(const float* x,
              const float* W0, const float* b0, const float* W1, const float* b1,
              const float* W2, const float* b2, const float* W3, const float* b3,
              const float* Wout, const float* bout,
              unsigned* H0, unsigned* H1, unsigned* H2, unsigned* flags,
              float* out, int layer_base, int pipe)
{
    const int layer = layer_base + (int)(blockIdx.x >> 5);
    const int chunk = (int)(blockIdx.x & 31);
    const bool p = (pipe != 0);
    if (layer == 0)
        run_layer<100, 100,  64, 6, 4, true,  true,  false>(chunk, p,
            x, nullptr, nullptr, W0, b0, H0, flags + 0, nullptr, nullptr, nullptr);
    else if (layer == 1)
        run_layer< 80,  80, 100, 6, 3, false, true,  false>(chunk, p,
            nullptr, H0, flags + 0, W1, b1, H1, flags + 32, nullptr, nullptr, nullptr);
    else if (layer == 2)
        run_layer< 50,  52,  80, 5, 2, false, true,  false>(chunk, p,
            nullptr, H1, flags + 32, W2, b2, H2, flags + 64, nullptr, nullptr, nullptr);
    else
        run_layer< 30,  32,  50, 3, 1, false, false, true >(chunk, p,
            nullptr, H2, flags + 64, W3, b3, nullptr, nullptr, Wout, bout, out);
}

extern "C" void kernel_launch(void* const* d_in, const int* in_sizes, int n_in,
                              void* d_out, int out_size, void* d_ws, size_t ws_size,
                              hipStream_t stream)
{
    const float* x    = (const float*)d_in[0];
    const float* W0   = (const float*)d_in[1];
    const float* b0   = (const float*)d_in[2];
    const float* W1   = (const float*)d_in[3];
    const float* b1   = (const float*)d_in[4];
    const float* W2   = (const float*)d_in[5];
    const float* b2   = (const float*)d_in[6];
    const float* W3   = (const float*)d_in[7];
    const float* b3   = (const float*)d_in[8];
    const float* Wout = (const float*)d_in[9];
    const float* bout = (const float*)d_in[10];
    float* out = (float*)d_out;

    const size_t H0e = (size_t)B_TOT * T_SEQ * 100;
    const size_t H1e = (size_t)B_TOT * T_SEQ * 80;
    const size_t H2e = (size_t)B_TOT * T_SEQ * 50;

    unsigned* H0 = (unsigned*)d_ws;
    const size_t need = (H0e + H1e + H2e + 256) * sizeof(unsigned);

    if (ws_size >= need) {
        // ---- pipelined: 128 persistent blocks, flags in d_ws tail ----
        unsigned* H1    = H0 + H0e;
        unsigned* H2    = H1 + H1e;
        unsigned* flags = H2 + H2e;
        hipLaunchKernelGGL(zero_flags, dim3(1), dim3(128), 0, stream, flags);
        hipLaunchKernelGGL(lstm_all, dim3(128), dim3(512), 0, stream,
                           x, W0, b0, W1, b1, W2, b2, W3, b3, Wout, bout,
                           H0, H1, H2, flags, out, 0, 1);
    } else {
        // ---- fallback: 4 sequential launches (H2 aliases H0), no flags ----
        unsigned* H1 = H0 + H0e;
        unsigned* H2 = H0;
        for (int l = 0; l < 4; ++l)
            hipLaunchKernelGGL(lstm_all, dim3(32), dim3(512), 0, stream,
                               x, W0, b0, W1, b1, W2, b2, W3, b3, Wout, bout,
                               H0, H1, H2, H2 /*flags unused*/, out, l, 0);
    }
}

// Round 13
// 4380.861 us; speedup vs baseline: 3.0169x; 3.0169x over previous
//
#include <hip/hip_runtime.h>

// Stacked LSTM (100/80/50/30) + dense head, fp32 semantics via bf16x3 MFMA.
//
// R13: unbundle R12. Keep R11's sequential per-layer structure (proven:
// absmax 3.8e-6) and apply ONLY the coalesced-H fix:
//   - R11 stored h scattered: lane -> Hpk[(row)*T*U + ...], 200KB apart
//     per lane = 64 lines per store instr, ~2048 scattered transactions
//     per block-step. That matches the 6700cyc/step latency gap (MfmaUtil
//     3.4%, VALUBusy 7.5% at 1432us L0).
//   - Fix: h lives in LDS (Abuf) anyway; at step t+1 store h(t) with
//     threads mapped to consecutive [row][t][u] addresses (16 contiguous
//     400B runs), retiring under the MFMAs. Consumer loads coalesced the
//     same way.
//   - NO pipelining, NO flags, NO per-step __threadfence (R12's 26us/step
//     disaster): 4 sequential launches.
//
// Kernel internals otherwise = R11: operand-swapped MFMA (A = W^T tile,
// gate-permuted cols -> lane-local cell update), weights bf16 hi/lo pinned
// to AGPRs (MFMA reads AGPRs natively), 1 barrier/step, bf16x3 numerics.

#define T_SEQ 512
#define B_TOT 512

typedef __attribute__((ext_vector_type(8))) short short8;   // 8 bf16
typedef __attribute__((ext_vector_type(4))) float f32x4;

__device__ __forceinline__ unsigned short bf16_rne(float f) {
    unsigned u = __float_as_uint(f);
    u += 0x7FFFu + ((u >> 16) & 1u);
    return (unsigned short)(u >> 16);
}
__device__ __forceinline__ float bf16_to_f(unsigned short h) {
    return __uint_as_float(((unsigned)h) << 16);
}
__device__ __forceinline__ float sigmoidf_(float x) {
    return 1.0f / (1.0f + __expf(-x));
}
__device__ __forceinline__ float tanh_fast(float x) {
    float e = __expf(2.0f * x);
    return 1.0f - 2.0f / (1.0f + e);
}

// U: real units, UP: padded units (mult 4), FI: input feats, KT: K-tiles of
// 32, SLOTS: weight slots/wave. XF32: input is fp32 (layer 0). SEQ: publish
// hidden sequence (layout [row][t][u], u32 = bf16 hi|lo<<16). FINAL: head.
template<int U, int UP, int FI, int KT, int SLOTS, bool XF32, bool SEQ, bool FINAL>
__device__ __forceinline__ void run_layer(
    int chunk,
    const float* Xf, const unsigned* Hin,
    const float* W, const float* Bv,
    unsigned* Hout,
    const float* Wd, const float* bd, float* OUT)
{
    constexpr int DIN  = U + FI;
    constexpr int G    = 4 * U;
    constexpr int NT   = UP / 4;
    constexpr int KP   = KT * 32;
    static_assert(KP >= DIN, "K padding must cover DIN");
    constexpr int KPPS = KT * 32 + 8;                  // row stride (shorts)
    constexpr int XIT  = XF32 ? 1 : (16 * FI + 511) / 512;
    constexpr int SIT  = SEQ ? (16 * U + 511) / 512 : 1;
    static_assert(8 * SLOTS >= NT, "slots must cover tiles");

    __shared__ __align__(16) short Abuf[2][2][16][KPPS];   // [buf][plane][row][k]
    __shared__ __align__(16) f32x4 btab[NT * 4];
    __shared__ float redu[8][16];

    const int tid  = threadIdx.x;
    const int wid  = tid >> 6;
    const int l15  = tid & 15;
    const int l4   = (tid >> 4) & 3;
    const int brow = chunk * 16;

    // ---- weight fragments (bf16 hi/lo), permuted cols, pinned to AGPR ----
    short8 Wh[SLOTS][KT], Wl[SLOTS][KT];
    #pragma unroll
    for (int s = 0; s < SLOTS; ++s) {
        const int ti = wid + 8 * s;
        #pragma unroll
        for (int kt = 0; kt < KT; ++kt) {
            short8 hh, ll;
            #pragma unroll
            for (int j = 0; j < 8; ++j) {
                const int k    = kt * 32 + l4 * 8 + j;
                const int up   = ti * 4 + (l15 >> 2);
                const int gate = l15 & 3;
                float v = 0.0f;
                if (ti < NT && up < U && k < DIN)
                    v = W[(size_t)k * G + gate * U + up];
                const unsigned short hb = bf16_rne(v);
                hh[j] = (short)hb;
                ll[j] = (short)bf16_rne(v - bf16_to_f(hb));
            }
            Wh[s][kt] = hh; Wl[s][kt] = ll;
            asm("" : "+a"(Wh[s][kt]));
            asm("" : "+a"(Wl[s][kt]));
        }
    }

    // ---- bias table ----
    if (tid < NT * 4) {
        f32x4 b = {0.f, 0.f, 0.f, 0.f};
        if (tid < U) { b[0]=Bv[tid]; b[1]=Bv[U+tid]; b[2]=Bv[2*U+tid]; b[3]=Bv[3*U+tid]; }
        btab[tid] = b;
    }

    // ---- consumer (x-in) coalesced map: idx -> (row, u) ----
    int crow[XIT], cu_[XIT]; bool cok[XIT]; size_t cbase[XIT];
    if constexpr (!XF32) {
        #pragma unroll
        for (int it = 0; it < XIT; ++it) {
            const int idx = it * 512 + tid;
            cok[it]  = (idx < 16 * FI);
            crow[it] = cok[it] ? (idx / FI) : 0;
            cu_[it]  = cok[it] ? (idx % FI) : 0;
            cbase[it] = (size_t)(brow + crow[it]) * T_SEQ * FI + cu_[it];
        }
    }
    const int xrow = tid >> 5, xj = (tid & 31) * 2;    // L0: 2 floats/thread
    size_t xfb = 0;
    if constexpr (XF32) xfb = (size_t)(brow + xrow) * T_SEQ * FI + xj;

    // ---- producer (h-out) coalesced map ----
    int srow[SIT], su_[SIT]; bool sok[SIT]; size_t sbase[SIT];
    if constexpr (SEQ) {
        #pragma unroll
        for (int it = 0; it < SIT; ++it) {
            const int idx = it * 512 + tid;
            sok[it]  = (idx < 16 * U);
            srow[it] = sok[it] ? (idx / U) : 0;
            su_[it]  = sok[it] ? (idx % U) : 0;
            sbase[it] = (size_t)(brow + srow[it]) * T_SEQ * U + su_[it];
        }
    }

    // ---- init: zero act buffers; stage x(0) ----
    for (int i = tid; i < 2 * 2 * 16 * KPPS; i += 512) ((short*)Abuf)[i] = 0;
    __syncthreads();
    if constexpr (XF32) {
        const float2 xv = *(const float2*)&Xf[xfb];
        const unsigned short h0 = bf16_rne(xv.x), h1 = bf16_rne(xv.y);
        Abuf[0][0][xrow][U + xj]     = (short)h0;
        Abuf[0][0][xrow][U + xj + 1] = (short)h1;
        Abuf[0][1][xrow][U + xj]     = (short)bf16_rne(xv.x - bf16_to_f(h0));
        Abuf[0][1][xrow][U + xj + 1] = (short)bf16_rne(xv.y - bf16_to_f(h1));
    } else {
        #pragma unroll
        for (int it = 0; it < XIT; ++it) if (cok[it]) {
            const unsigned v = Hin[cbase[it]];
            Abuf[0][0][crow[it]][U + cu_[it]] = (short)(v & 0xffffu);
            Abuf[0][1][crow[it]][U + cu_[it]] = (short)(v >> 16);
        }
    }
    __syncthreads();

    float c_[SLOTS], hl_[SLOTS];
    #pragma unroll
    for (int s = 0; s < SLOTS; ++s) { c_[s] = 0.0f; hl_[s] = 0.0f; }

    for (int t = 0; t < T_SEQ; ++t) {
        const int cur = t & 1, nxt = cur ^ 1;
        const bool dopre = (t + 1 < T_SEQ);

        // ---- consumer prefetch x(t+1) -> regs (overlaps MFMA) ----
        float2 xv;
        unsigned xg[XIT];
        if (dopre) {
            if constexpr (XF32) {
                xv = *(const float2*)&Xf[xfb + (size_t)(t + 1) * FI];
            } else {
                #pragma unroll
                for (int it = 0; it < XIT; ++it)
                    if (cok[it]) xg[it] = Hin[cbase[it] + (size_t)(t + 1) * FI];
            }
        }

        // ---- producer: coalesced store of h(t-1) from Abuf[cur] h-region
        //      (written by step t-1's cell phase; stable during step t;
        //      retires under the MFMAs below) ----
        if constexpr (SEQ) {
            if (t > 0) {
                #pragma unroll
                for (int it = 0; it < SIT; ++it) if (sok[it]) {
                    const unsigned v =
                        (unsigned)(unsigned short)Abuf[cur][0][srow[it]][su_[it]]
                      | ((unsigned)(unsigned short)Abuf[cur][1][srow[it]][su_[it]] << 16);
                    Hout[sbase[it] + (size_t)(t - 1) * U] = v;
                }
            }
        }

        // ---- GEMM: D = W^T-tiles x act, bf16x3 ----
        f32x4 acc[SLOTS];
        #pragma unroll
        for (int s = 0; s < SLOTS; ++s) {
            const int ti = wid + 8 * s;
            acc[s] = (ti < NT) ? btab[ti * 4 + l4] : (f32x4){0.f,0.f,0.f,0.f};
        }
        #pragma unroll
        for (int kt = 0; kt < KT; ++kt) {
            const short8 Ah = *(const short8*)&Abuf[cur][0][l15][kt * 32 + l4 * 8];
            const short8 Al = *(const short8*)&Abuf[cur][1][l15][kt * 32 + l4 * 8];
            #pragma unroll
            for (int s = 0; s < SLOTS; ++s) {
                if (wid + 8 * s < NT) {
                    acc[s] = __builtin_amdgcn_mfma_f32_16x16x32_bf16(Wh[s][kt], Ah, acc[s], 0, 0, 0);
                    acc[s] = __builtin_amdgcn_mfma_f32_16x16x32_bf16(Wl[s][kt], Ah, acc[s], 0, 0, 0);
                    acc[s] = __builtin_amdgcn_mfma_f32_16x16x32_bf16(Wh[s][kt], Al, acc[s], 0, 0, 0);
                }
            }
        }

        // ---- cell update (lane-local) -> Abuf[nxt] h-region ----
        #pragma unroll
        for (int s = 0; s < SLOTS; ++s) {
            const int ti = wid + 8 * s;
            if (ti < NT) {
                const float F  = sigmoidf_(acc[s][0]);
                const float I  = sigmoidf_(acc[s][1]);
                const float Gv = tanh_fast(acc[s][2]);
                const float O  = sigmoidf_(acc[s][3]);
                c_[s] = F * c_[s] + I * Gv;
                const float h = O * tanh_fast(c_[s]);
                hl_[s] = h;
                const int up = ti * 4 + l4;
                if (up < U) {
                    const unsigned short hh = bf16_rne(h);
                    const unsigned short hl = bf16_rne(h - bf16_to_f(hh));
                    Abuf[nxt][0][l15][up] = (short)hh;
                    Abuf[nxt][1][l15][up] = (short)hl;
                }
            }
        }

        // ---- stage x(t+1) -> Abuf[nxt] x-region ----
        if (dopre) {
            if constexpr (XF32) {
                const unsigned short h0 = bf16_rne(xv.x), h1 = bf16_rne(xv.y);
                Abuf[nxt][0][xrow][U + xj]     = (short)h0;
                Abuf[nxt][0][xrow][U + xj + 1] = (short)h1;
                Abuf[nxt][1][xrow][U + xj]     = (short)bf16_rne(xv.x - bf16_to_f(h0));
                Abuf[nxt][1][xrow][U + xj + 1] = (short)bf16_rne(xv.y - bf16_to_f(h1));
            } else {
                #pragma unroll
                for (int it = 0; it < XIT; ++it) if (cok[it]) {
                    Abuf[nxt][0][crow[it]][U + cu_[it]] = (short)(xg[it] & 0xffffu);
                    Abuf[nxt][1][crow[it]][U + cu_[it]] = (short)(xg[it] >> 16);
                }
            }
        }
        __syncthreads();
    }

    // ---- post-loop: publish h(511) (lives in Abuf[0], T_SEQ even) ----
    if constexpr (SEQ) {
        #pragma unroll
        for (int it = 0; it < SIT; ++it) if (sok[it]) {
            const unsigned v =
                (unsigned)(unsigned short)Abuf[0][0][srow[it]][su_[it]]
              | ((unsigned)(unsigned short)Abuf[0][1][srow[it]][su_[it]] << 16);
            Hout[sbase[it] + (size_t)(T_SEQ - 1) * U] = v;
        }
    }

    if constexpr (FINAL) {
        const int up = wid * 4 + l4;
        float p = 0.0f;
        if (up < U) p = hl_[0] * Wd[up];
        p += __shfl_xor(p, 16, 64);
        p += __shfl_xor(p, 32, 64);
        if ((tid & 48) == 0) redu[wid][l15] = p;
        __syncthreads();
        if (tid < 16) {
            float a = bd[0];
            #pragma unroll
            for (int w2 = 0; w2 < 8; ++w2) a += redu[w2][tid];
            OUT[brow + tid] = a;
        }
    }
}

__global__ __launch_bounds__(512, 1)
void lstm_all(const float* x,
              const float* W0, const float* b0, const float* W1, const float* b1,
              const float* W2, const float* b2, const float* W3, const float* b3,
              const float* Wout, const float* bout,
              unsigned* H0, unsigned* H1, unsigned* H2,
              float* out, int layer)
{
    const int chunk = (int)blockIdx.x;
    if (layer == 0)
        run_layer<100, 100,  64, 6, 4, true,  true,  false>(chunk,
            x, nullptr, W0, b0, H0, nullptr, nullptr, nullptr);
    else if (layer == 1)
        run_layer< 80,  80, 100, 6, 3, false, true,  false>(chunk,
            nullptr, H0, W1, b1, H1, nullptr, nullptr, nullptr);
    else if (layer == 2)
        run_layer< 50,  52,  80, 5, 2, false, true,  false>(chunk,
            nullptr, H1, W2, b2, H2, nullptr, nullptr, nullptr);
    else
        run_layer< 30,  32,  50, 3, 1, false, false, true >(chunk,
            nullptr, H2, W3, b3, nullptr, Wout, bout, out);
}

extern "C" void kernel_launch(void* const* d_in, const int* in_sizes, int n_in,
                              void* d_out, int out_size, void* d_ws, size_t ws_size,
                              hipStream_t stream)
{
    const float* x    = (const float*)d_in[0];
    const float* W0   = (const float*)d_in[1];
    const float* b0   = (const float*)d_in[2];
    const float* W1   = (const float*)d_in[3];
    const float* b1   = (const float*)d_in[4];
    const float* W2   = (const float*)d_in[5];
    const float* b2   = (const float*)d_in[6];
    const float* W3   = (const float*)d_in[7];
    const float* b3   = (const float*)d_in[8];
    const float* Wout = (const float*)d_in[9];
    const float* bout = (const float*)d_in[10];
    float* out = (float*)d_out;

    const size_t H0e = (size_t)B_TOT * T_SEQ * 100;
    const size_t H1e = (size_t)B_TOT * T_SEQ * 80;
    const size_t H2e = (size_t)B_TOT * T_SEQ * 50;

    unsigned* H0 = (unsigned*)d_ws;
    unsigned* H1 = H0 + H0e;
    // H2 gets its own slot if workspace allows; else alias H0 (safe:
    // sequential launches, H0 dead once layer 2 runs).
    unsigned* H2 = (ws_size >= (H0e + H1e + H2e) * sizeof(unsigned))
                 ? (H1 + H1e) : H0;

    for (int l = 0; l < 4; ++l)
        hipLaunchKernelGGL(lstm_all, dim3(32), dim3(512), 0, stream,
                           x, W0, b0, W1, b1, W2, b2, W3, b3, Wout, bout,
                           H0, H1, H2, out, l);
}